// Round 6
// baseline (296.613 us; speedup 1.0000x reference)
//
#include <hip/hip_runtime.h>

#define MAX_RIGID 8

// X,Y,O are 4x3 affine: [0..8] rot row-major, [9..11] translation
__device__ __forceinline__ void combine12(const float* X, const float* Y, float* O) {
    #pragma unroll
    for (int i = 0; i < 3; ++i) {
        #pragma unroll
        for (int k = 0; k < 3; ++k)
            O[i*3+k] = X[i*3+0]*Y[0+k] + X[i*3+1]*Y[3+k] + X[i*3+2]*Y[6+k];
        O[9+i] = X[i*3+0]*Y[9] + X[i*3+1]*Y[10] + X[i*3+2]*Y[11] + X[9+i];
    }
}

__device__ __forceinline__ void atom_xyz(const float opr[MAX_RIGID][12], int g,
                                         float gx, float gy, float gz,
                                         float& x, float& y, float& z)
{
    float O[12];
    #pragma unroll
    for (int j = 0; j < 12; ++j) O[j] = opr[0][j];
    #pragma unroll
    for (int cnd = 1; cnd < MAX_RIGID; ++cnd) {
        bool take = (g == cnd);
        #pragma unroll
        for (int j = 0; j < 12; ++j) O[j] = take ? opr[cnd][j] : O[j];
    }
    x = O[0]*gx + O[1]*gy + O[2]*gz + O[9];
    y = O[3]*gx + O[4]*gy + O[5]*gz + O[10];
    z = O[6]*gx + O[7]*gy + O[8]*gz + O[11];
}

// Tables in LDS, residue stride padded to 100 dwords (100 mod 32 = 4):
// distinct rt -> distinct bank groups (<=3-way among 22 types), 16B-aligned.
__global__ __launch_bounds__(256, 5) void build_struct_kernel(
    const float* __restrict__ out0,   // [N,14]
    const float* __restrict__ out1,   // [N,9]
    const float* __restrict__ pos,    // [N,3]
    const float* __restrict__ rigidT, // [22,8,12]
    const float* __restrict__ rigidG, // [22,24,3]
    const int*   __restrict__ resty,  // [N]
    const int*   __restrict__ tdep,   // [22,8]
    const int*   __restrict__ gdep,   // [22,24]
    const int*   __restrict__ nrp,
    float* __restrict__ dR,           // [N,72]
    float* __restrict__ dOprBB,       // [N,12]
    float* __restrict__ dBB,          // [N,12]
    float* __restrict__ dSC,          // [N,14]
    int N)
{
    __shared__ float sT[2200];   // [22][100]: T of residue r at sT[r*100 + 0..95]
    __shared__ float sG[2200];   // [22][100]: atom a at sG[r*100 + a*4 + {0,1,2}]
    __shared__ int   sgd[616];   // [22][28]
    __shared__ int   stdp[264]; // [22][12]

    const int tid = threadIdx.x;

    // ---- table staging (one-time, coalesced) ----
    for (int i = tid; i < 2112; i += 256) { int r = i / 96;  sT[r*100 + (i - r*96)] = rigidT[i]; }
    for (int i = tid; i < 1584; i += 256) { int r = i / 72;  int q = i - r*72; int a = q / 3;
                                            sG[r*100 + a*4 + (q - a*3)] = rigidG[i]; }
    for (int i = tid; i < 528;  i += 256) { int r = i / 24;  sgd[r*28 + (i - r*24)] = gdep[i]; }
    for (int i = tid; i < 176;  i += 256) { int r = i >> 3;  stdp[r*12 + (i & 7)]   = tdep[i]; }
    __syncthreads();   // only barrier in the kernel

    long n = (long)blockIdx.x * 256 + tid;
    if (n >= N) return;

    int iv = *nrp;
    float nrv = (iv > 0 && iv < 1000000) ? (float)iv
                                         : *reinterpret_cast<const float*>(nrp);
    float tscale = 0.1f / nrv;

    // ---- per-lane input loads ----
    float o0r[14];
    {
        const float2* p = reinterpret_cast<const float2*>(out0 + (size_t)n * 14);
        #pragma unroll
        for (int k = 0; k < 7; ++k) { float2 v = p[k]; o0r[2*k] = v.x; o0r[2*k+1] = v.y; }
    }
    float o1r[9];
    {
        const float* p = out1 + (size_t)n * 9;
        #pragma unroll
        for (int k = 0; k < 9; ++k) o1r[k] = p[k];
    }
    float px = pos[(size_t)n*3+0], py = pos[(size_t)n*3+1], pz = pos[(size_t)n*3+2];
    int rt = resty[n];

    // ---- sc (v_rsq_f32) ----
    float sc[14];
    #pragma unroll
    for (int k = 0; k < 7; ++k) {
        float a = o0r[2*k], b = o0r[2*k+1];
        float r = __builtin_amdgcn_rsqf(a*a + b*b + 1e-12f);
        sc[2*k] = a*r; sc[2*k+1] = b*r;
    }
    // ---- bb ----
    float bb[12];
    {
        float v0x=o1r[0], v0y=o1r[1], v0z=o1r[2];
        float v1x=o1r[3], v1y=o1r[4], v1z=o1r[5];
        float r0 = __builtin_amdgcn_rsqf(v0x*v0x + v0y*v0y + v0z*v0z + 1e-12f);
        float e0x=v0x*r0, e0y=v0y*r0, e0z=v0z*r0;
        float dp = e0x*v1x + e0y*v1y + e0z*v1z;
        float u1x = v1x - e0x*dp, u1y = v1y - e0y*dp, u1z = v1z - e0z*dp;
        float r1 = __builtin_amdgcn_rsqf(u1x*u1x + u1y*u1y + u1z*u1z + 1e-12f);
        float e1x=u1x*r1, e1y=u1y*r1, e1z=u1z*r1;
        float e2x = e0y*e1z - e0z*e1y;
        float e2y = e0z*e1x - e0x*e1z;
        float e2z = e0x*e1y - e0y*e1x;
        bb[0]=e0x; bb[1]=e1x; bb[2]=e2x;
        bb[3]=e0y; bb[4]=e1y; bb[5]=e2y;
        bb[6]=e0z; bb[7]=e1z; bb[8]=e2z;
        bb[9]=tscale*o1r[6]; bb[10]=tscale*o1r[7]; bb[11]=tscale*o1r[8];
    }

    // ---- table gathers from LDS (padded strides) ----
    const float4* T4 = reinterpret_cast<const float4*>(sT + rt * 100);
    int tdr[8];
    {
        const int4* t4 = reinterpret_cast<const int4*>(stdp + rt * 12);
        int4 a = t4[0], b = t4[1];
        tdr[0]=a.x; tdr[1]=a.y; tdr[2]=a.z; tdr[3]=a.w;
        tdr[4]=b.x; tdr[5]=b.y; tdr[6]=b.z; tdr[7]=b.w;
    }

    // ---- rigid chain ----
    float opr[MAX_RIGID][12];
    {
        float X[12];
        { float4 r0v=T4[0], r1v=T4[1], r2v=T4[2];
          X[0]=r0v.x; X[1]=r0v.y; X[2]=r0v.z; X[3]=r0v.w;
          X[4]=r1v.x; X[5]=r1v.y; X[6]=r1v.z; X[7]=r1v.w;
          X[8]=r2v.x; X[9]=r2v.y; X[10]=r2v.z; X[11]=r2v.w; }
        float Y[12] = { bb[0],bb[1],bb[2], bb[3],bb[4],bb[5], bb[6],bb[7],bb[8],
                        bb[9]+px, bb[10]+py, bb[11]+pz };
        combine12(X, Y, opr[0]);
    }
    #pragma unroll
    for (int i = 1; i < MAX_RIGID; ++i) {
        float X[12];
        { float4 r0v=T4[i*3], r1v=T4[i*3+1], r2v=T4[i*3+2];
          X[0]=r0v.x; X[1]=r0v.y; X[2]=r0v.z; X[3]=r0v.w;
          X[4]=r1v.x; X[5]=r1v.y; X[6]=r1v.z; X[7]=r1v.w;
          X[8]=r2v.x; X[9]=r2v.y; X[10]=r2v.z; X[11]=r2v.w; }
        float c = sc[2*(i-1)], s = sc[2*(i-1)+1];
        float M[12];
        M[0]=X[0]; M[3]=X[3]; M[6]=X[6];
        M[1] = c*X[1] + s*X[2];   M[2] = c*X[2] - s*X[1];
        M[4] = c*X[4] + s*X[5];   M[5] = c*X[5] - s*X[4];
        M[7] = c*X[7] + s*X[8];   M[8] = c*X[8] - s*X[7];
        M[9]=X[9]; M[10]=X[10]; M[11]=X[11];
        int t = tdr[i];
        float P[12];
        #pragma unroll
        for (int j = 0; j < 12; ++j) P[j] = opr[0][j];
        #pragma unroll
        for (int cnd = 1; cnd < i; ++cnd) {
            bool take = (t == cnd);
            #pragma unroll
            for (int j = 0; j < 12; ++j) P[j] = take ? opr[cnd][j] : P[j];
        }
        combine12(P, M, opr[i]);
    }

    // ---- small outputs: direct vectorized stores ----
    {
        float2* d0 = reinterpret_cast<float2*>(dSC + (size_t)n * 14);
        #pragma unroll
        for (int k = 0; k < 7; ++k) d0[k] = make_float2(sc[2*k], sc[2*k+1]);
        float4* d1 = reinterpret_cast<float4*>(dBB + (size_t)n * 12);
        #pragma unroll
        for (int k = 0; k < 3; ++k) d1[k] = make_float4(bb[4*k], bb[4*k+1], bb[4*k+2], bb[4*k+3]);
        float4* d2 = reinterpret_cast<float4*>(dOprBB + (size_t)n * 12);
        #pragma unroll
        for (int k = 0; k < 3; ++k) d2[k] = make_float4(opr[0][4*k], opr[0][4*k+1], opr[0][4*k+2], opr[0][4*k+3]);
    }

    // ---- atoms: 3 chunks x 8, direct f4 stores ----
    const float4* G4  = reinterpret_cast<const float4*>(sG + rt * 100);
    const int4*   gd4 = reinterpret_cast<const int4*>(sgd + rt * 28);
    float* Rout = dR + (size_t)n * 72;
    #pragma unroll
    for (int c = 0; c < 3; ++c) {
        int4 ga = gd4[c*2], gb = gd4[c*2+1];
        int gch[8] = {ga.x, ga.y, ga.z, ga.w, gb.x, gb.y, gb.z, gb.w};
        float rbuf[24];
        #pragma unroll
        for (int a4 = 0; a4 < 8; ++a4) {
            int a = c*8 + a4;
            float4 gv = G4[a];
            float x, y, z;
            atom_xyz(opr, gch[a4], gv.x, gv.y, gv.z, x, y, z);
            rbuf[a4*3+0] = x; rbuf[a4*3+1] = y; rbuf[a4*3+2] = z;
        }
        float4* dst = reinterpret_cast<float4*>(Rout + c * 24);
        #pragma unroll
        for (int q = 0; q < 6; ++q)
            dst[q] = make_float4(rbuf[4*q], rbuf[4*q+1], rbuf[4*q+2], rbuf[4*q+3]);
    }
}

extern "C" void kernel_launch(void* const* d_in, const int* in_sizes, int n_in,
                              void* d_out, int out_size, void* d_ws, size_t ws_size,
                              hipStream_t stream) {
    const float* out0 = (const float*)d_in[0];
    const float* out1 = (const float*)d_in[1];
    const float* pos  = (const float*)d_in[2];
    const float* rT   = (const float*)d_in[3];
    const float* rG   = (const float*)d_in[4];
    const int*   res  = (const int*)d_in[5];
    const int*   td   = (const int*)d_in[6];
    const int*   gd   = (const int*)d_in[7];
    const int*   nr   = (const int*)d_in[8];

    int N = in_sizes[5];

    float* dR     = (float*)d_out;
    float* dOprBB = dR + (size_t)N * 72;
    float* dBB    = dOprBB + (size_t)N * 12;
    float* dSC    = dBB + (size_t)N * 12;

    dim3 grid((N + 255) / 256), block(256);
    hipLaunchKernelGGL(build_struct_kernel, grid, block, 0, stream,
                       out0, out1, pos, rT, rG, res, td, gd, nr,
                       dR, dOprBB, dBB, dSC, N);
}

// Round 7
// 74.587 us; speedup vs baseline: 3.9767x; 3.9767x over previous
//
#include <hip/hip_runtime.h>

#define MAX_RIGID 8

// X,Y,O are 4x3 affine: [0..8] rot row-major, [9..11] translation
__device__ __forceinline__ void combine12(const float* X, const float* Y, float* O) {
    #pragma unroll
    for (int i = 0; i < 3; ++i) {
        #pragma unroll
        for (int k = 0; k < 3; ++k)
            O[i*3+k] = X[i*3+0]*Y[0+k] + X[i*3+1]*Y[3+k] + X[i*3+2]*Y[6+k];
        O[9+i] = X[i*3+0]*Y[9] + X[i*3+1]*Y[10] + X[i*3+2]*Y[11] + X[9+i];
    }
}

__device__ __forceinline__ void atom_xyz(const float opr[MAX_RIGID][12], int g,
                                         float gx, float gy, float gz,
                                         float& x, float& y, float& z)
{
    float O[12];
    #pragma unroll
    for (int j = 0; j < 12; ++j) O[j] = opr[0][j];
    #pragma unroll
    for (int cnd = 1; cnd < MAX_RIGID; ++cnd) {
        bool take = (g == cnd);
        #pragma unroll
        for (int j = 0; j < 12; ++j) O[j] = take ? opr[cnd][j] : O[j];
    }
    x = O[0]*gx + O[1]*gy + O[2]*gz + O[9];
    y = O[3]*gx + O[4]*gy + O[5]*gz + O[10];
    z = O[6]*gx + O[7]*gy + O[8]*gz + O[11];
}

// Tables in LDS, residue stride padded to 100 dwords (100 mod 32 = 4):
// distinct rt -> distinct bank groups, 16B-aligned.
// NOTE: no min-waves clause — R6's __launch_bounds__(256,5) capped VGPR at 48
// and spilled the 96-float opr array to scratch (FETCH 315MB / WRITE 675MB).
__global__ __launch_bounds__(256) void build_struct_kernel(
    const float* __restrict__ out0,   // [N,14]
    const float* __restrict__ out1,   // [N,9]
    const float* __restrict__ pos,    // [N,3]
    const float* __restrict__ rigidT, // [22,8,12]
    const float* __restrict__ rigidG, // [22,24,3]
    const int*   __restrict__ resty,  // [N]
    const int*   __restrict__ tdep,   // [22,8]
    const int*   __restrict__ gdep,   // [22,24]
    const int*   __restrict__ nrp,
    float* __restrict__ dR,           // [N,72]
    float* __restrict__ dOprBB,       // [N,12]
    float* __restrict__ dBB,          // [N,12]
    float* __restrict__ dSC,          // [N,14]
    int N)
{
    __shared__ float sT[2200];   // [22][100]: T of residue r at sT[r*100 + 0..95]
    __shared__ float sG[2200];   // [22][100]: atom a at sG[r*100 + a*4 + {0,1,2}]
    __shared__ int   sgd[616];   // [22][28]
    __shared__ int   stdp[264];  // [22][12]

    const int tid = threadIdx.x;

    // ---- table staging (one-time, coalesced) ----
    for (int i = tid; i < 2112; i += 256) { int r = i / 96;  sT[r*100 + (i - r*96)] = rigidT[i]; }
    for (int i = tid; i < 1584; i += 256) { int r = i / 72;  int q = i - r*72; int a = q / 3;
                                            sG[r*100 + a*4 + (q - a*3)] = rigidG[i]; }
    for (int i = tid; i < 528;  i += 256) { int r = i / 24;  sgd[r*28 + (i - r*24)] = gdep[i]; }
    for (int i = tid; i < 176;  i += 256) { int r = i >> 3;  stdp[r*12 + (i & 7)]   = tdep[i]; }
    __syncthreads();   // only barrier in the kernel

    long n = (long)blockIdx.x * 256 + tid;
    if (n >= N) return;

    int iv = *nrp;
    float nrv = (iv > 0 && iv < 1000000) ? (float)iv
                                         : *reinterpret_cast<const float*>(nrp);
    float tscale = 0.1f / nrv;

    // ---- per-lane input loads ----
    float o0r[14];
    {
        const float2* p = reinterpret_cast<const float2*>(out0 + (size_t)n * 14);
        #pragma unroll
        for (int k = 0; k < 7; ++k) { float2 v = p[k]; o0r[2*k] = v.x; o0r[2*k+1] = v.y; }
    }
    float o1r[9];
    {
        const float* p = out1 + (size_t)n * 9;
        #pragma unroll
        for (int k = 0; k < 9; ++k) o1r[k] = p[k];
    }
    float px = pos[(size_t)n*3+0], py = pos[(size_t)n*3+1], pz = pos[(size_t)n*3+2];
    int rt = resty[n];

    // ---- sc (v_rsq_f32) ----
    float sc[14];
    #pragma unroll
    for (int k = 0; k < 7; ++k) {
        float a = o0r[2*k], b = o0r[2*k+1];
        float r = __builtin_amdgcn_rsqf(a*a + b*b + 1e-12f);
        sc[2*k] = a*r; sc[2*k+1] = b*r;
    }
    // ---- bb ----
    float bb[12];
    {
        float v0x=o1r[0], v0y=o1r[1], v0z=o1r[2];
        float v1x=o1r[3], v1y=o1r[4], v1z=o1r[5];
        float r0 = __builtin_amdgcn_rsqf(v0x*v0x + v0y*v0y + v0z*v0z + 1e-12f);
        float e0x=v0x*r0, e0y=v0y*r0, e0z=v0z*r0;
        float dp = e0x*v1x + e0y*v1y + e0z*v1z;
        float u1x = v1x - e0x*dp, u1y = v1y - e0y*dp, u1z = v1z - e0z*dp;
        float r1 = __builtin_amdgcn_rsqf(u1x*u1x + u1y*u1y + u1z*u1z + 1e-12f);
        float e1x=u1x*r1, e1y=u1y*r1, e1z=u1z*r1;
        float e2x = e0y*e1z - e0z*e1y;
        float e2y = e0z*e1x - e0x*e1z;
        float e2z = e0x*e1y - e0y*e1x;
        bb[0]=e0x; bb[1]=e1x; bb[2]=e2x;
        bb[3]=e0y; bb[4]=e1y; bb[5]=e2y;
        bb[6]=e0z; bb[7]=e1z; bb[8]=e2z;
        bb[9]=tscale*o1r[6]; bb[10]=tscale*o1r[7]; bb[11]=tscale*o1r[8];
    }

    // ---- table gathers from LDS (padded strides) ----
    const float4* T4 = reinterpret_cast<const float4*>(sT + rt * 100);
    int tdr[8];
    {
        const int4* t4 = reinterpret_cast<const int4*>(stdp + rt * 12);
        int4 a = t4[0], b = t4[1];
        tdr[0]=a.x; tdr[1]=a.y; tdr[2]=a.z; tdr[3]=a.w;
        tdr[4]=b.x; tdr[5]=b.y; tdr[6]=b.z; tdr[7]=b.w;
    }

    // ---- rigid chain ----
    float opr[MAX_RIGID][12];
    {
        float X[12];
        { float4 r0v=T4[0], r1v=T4[1], r2v=T4[2];
          X[0]=r0v.x; X[1]=r0v.y; X[2]=r0v.z; X[3]=r0v.w;
          X[4]=r1v.x; X[5]=r1v.y; X[6]=r1v.z; X[7]=r1v.w;
          X[8]=r2v.x; X[9]=r2v.y; X[10]=r2v.z; X[11]=r2v.w; }
        float Y[12] = { bb[0],bb[1],bb[2], bb[3],bb[4],bb[5], bb[6],bb[7],bb[8],
                        bb[9]+px, bb[10]+py, bb[11]+pz };
        combine12(X, Y, opr[0]);
    }
    #pragma unroll
    for (int i = 1; i < MAX_RIGID; ++i) {
        float X[12];
        { float4 r0v=T4[i*3], r1v=T4[i*3+1], r2v=T4[i*3+2];
          X[0]=r0v.x; X[1]=r0v.y; X[2]=r0v.z; X[3]=r0v.w;
          X[4]=r1v.x; X[5]=r1v.y; X[6]=r1v.z; X[7]=r1v.w;
          X[8]=r2v.x; X[9]=r2v.y; X[10]=r2v.z; X[11]=r2v.w; }
        float c = sc[2*(i-1)], s = sc[2*(i-1)+1];
        float M[12];
        M[0]=X[0]; M[3]=X[3]; M[6]=X[6];
        M[1] = c*X[1] + s*X[2];   M[2] = c*X[2] - s*X[1];
        M[4] = c*X[4] + s*X[5];   M[5] = c*X[5] - s*X[4];
        M[7] = c*X[7] + s*X[8];   M[8] = c*X[8] - s*X[7];
        M[9]=X[9]; M[10]=X[10]; M[11]=X[11];
        int t = tdr[i];
        float P[12];
        #pragma unroll
        for (int j = 0; j < 12; ++j) P[j] = opr[0][j];
        #pragma unroll
        for (int cnd = 1; cnd < i; ++cnd) {
            bool take = (t == cnd);
            #pragma unroll
            for (int j = 0; j < 12; ++j) P[j] = take ? opr[cnd][j] : P[j];
        }
        combine12(P, M, opr[i]);
    }

    // ---- small outputs: direct vectorized stores ----
    {
        float2* d0 = reinterpret_cast<float2*>(dSC + (size_t)n * 14);
        #pragma unroll
        for (int k = 0; k < 7; ++k) d0[k] = make_float2(sc[2*k], sc[2*k+1]);
        float4* d1 = reinterpret_cast<float4*>(dBB + (size_t)n * 12);
        #pragma unroll
        for (int k = 0; k < 3; ++k) d1[k] = make_float4(bb[4*k], bb[4*k+1], bb[4*k+2], bb[4*k+3]);
        float4* d2 = reinterpret_cast<float4*>(dOprBB + (size_t)n * 12);
        #pragma unroll
        for (int k = 0; k < 3; ++k) d2[k] = make_float4(opr[0][4*k], opr[0][4*k+1], opr[0][4*k+2], opr[0][4*k+3]);
    }

    // ---- atoms: 3 chunks x 8, direct f4 stores ----
    const float4* G4  = reinterpret_cast<const float4*>(sG + rt * 100);
    const int4*   gd4 = reinterpret_cast<const int4*>(sgd + rt * 28);
    float* Rout = dR + (size_t)n * 72;
    #pragma unroll
    for (int c = 0; c < 3; ++c) {
        int4 ga = gd4[c*2], gb = gd4[c*2+1];
        int gch[8] = {ga.x, ga.y, ga.z, ga.w, gb.x, gb.y, gb.z, gb.w};
        float rbuf[24];
        #pragma unroll
        for (int a4 = 0; a4 < 8; ++a4) {
            int a = c*8 + a4;
            float4 gv = G4[a];
            float x, y, z;
            atom_xyz(opr, gch[a4], gv.x, gv.y, gv.z, x, y, z);
            rbuf[a4*3+0] = x; rbuf[a4*3+1] = y; rbuf[a4*3+2] = z;
        }
        float4* dst = reinterpret_cast<float4*>(Rout + c * 24);
        #pragma unroll
        for (int q = 0; q < 6; ++q)
            dst[q] = make_float4(rbuf[4*q], rbuf[4*q+1], rbuf[4*q+2], rbuf[4*q+3]);
    }
}

extern "C" void kernel_launch(void* const* d_in, const int* in_sizes, int n_in,
                              void* d_out, int out_size, void* d_ws, size_t ws_size,
                              hipStream_t stream) {
    const float* out0 = (const float*)d_in[0];
    const float* out1 = (const float*)d_in[1];
    const float* pos  = (const float*)d_in[2];
    const float* rT   = (const float*)d_in[3];
    const float* rG   = (const float*)d_in[4];
    const int*   res  = (const int*)d_in[5];
    const int*   td   = (const int*)d_in[6];
    const int*   gd   = (const int*)d_in[7];
    const int*   nr   = (const int*)d_in[8];

    int N = in_sizes[5];

    float* dR     = (float*)d_out;
    float* dOprBB = dR + (size_t)N * 72;
    float* dBB    = dOprBB + (size_t)N * 12;
    float* dSC    = dBB + (size_t)N * 12;

    dim3 grid((N + 255) / 256), block(256);
    hipLaunchKernelGGL(build_struct_kernel, grid, block, 0, stream,
                       out0, out1, pos, rT, rG, res, td, gd, nr,
                       dR, dOprBB, dBB, dSC, N);
}